// Round 8
// baseline (131.453 us; speedup 1.0000x reference)
//
#include <hip/hip_runtime.h>
#include <hip/hip_bf16.h>
#include <stdint.h>

#define BATCH 16384
#define INF   1024
#define OUTF  2048

#define BM 256
#define BN 256
#define BK 64
#define NT (INF / BK)   // 16 K-tiles

using bf16x8 = __attribute__((ext_vector_type(8))) __bf16;
using f32x4  = __attribute__((ext_vector_type(4))) float;
typedef unsigned short u16;

// round-to-nearest-even f32 -> bf16 (bit pattern)
__device__ __forceinline__ u16 f2bf(float f) {
  unsigned u = __builtin_bit_cast(unsigned, f);
  u += 0x7fffu + ((u >> 16) & 1u);
  return (u16)(u >> 16);
}

__device__ __forceinline__ void load_lds16(const void* g, void* l) {
  __builtin_amdgcn_global_load_lds(
      (const __attribute__((address_space(1))) unsigned*)g,
      (__attribute__((address_space(3))) unsigned*)l, 16, 0, 0);
}

// ---- x: fp32 [BATCH][INF] -> bf16 [BATCH][INF] + row sum-of-squares (fp32) ----
__global__ void __launch_bounds__(256) k_convert_x(const float* __restrict__ x,
                                                   u16* __restrict__ xb,
                                                   float* __restrict__ xsq) {
  const int row = blockIdx.x;
  const int t = threadIdx.x;
  const float4 v = reinterpret_cast<const float4*>(x + (size_t)row * INF)[t];
  ushort4 b4;
  b4.x = f2bf(v.x); b4.y = f2bf(v.y); b4.z = f2bf(v.z); b4.w = f2bf(v.w);
  reinterpret_cast<ushort4*>(xb + (size_t)row * INF)[t] = b4;

  float s = v.x * v.x + v.y * v.y + v.z * v.z + v.w * v.w;
  #pragma unroll
  for (int off = 32; off > 0; off >>= 1) s += __shfl_xor(s, off, 64);
  __shared__ float red[4];
  if ((t & 63) == 0) red[t >> 6] = s;
  __syncthreads();
  if (t == 0) xsq[row] = red[0] + red[1] + red[2] + red[3];
}

// ---- w: fp32 [INF][OUTF] -> FRAGMENT-MAJOR bf16 B + fused per-column sq-partials ----
// Bf element index: (((bx*16 + t)*4 + wc)*8 + f)*512 + l*8 + j   (f = nn*2+ks)
// holds B^T[col][k] with col = bx*256+wc*64+nn*16+(l&15), k = t*64+ks*32+(l>>4)*8+j.
__global__ void __launch_bounds__(256) k_convert_w(const float* __restrict__ w,
                                                   u16* __restrict__ Bf,
                                                   float* __restrict__ part) {
  __shared__ float tile[64][65];   // [k][n]
  __shared__ float psum[4][64];
  const int n0 = blockIdx.x * 64;   // along OUTF
  const int k0 = blockIdx.y * 64;   // along INF
  const int tid = threadIdx.x;
  const int c = tid & 63, r4 = tid >> 6;
  float s = 0.f;
  #pragma unroll
  for (int i = 0; i < 16; ++i) {
    int k = r4 + i * 4;
    float v = w[(size_t)(k0 + k) * OUTF + n0 + c];   // coalesced over n
    tile[k][c] = v;
    s += v * v;
  }
  psum[r4][c] = s;
  __syncthreads();

  const int bx = blockIdx.x >> 2;          // 256-col block
  const int wc = blockIdx.x & 3;           // 64-col sub-block
  const int tt = blockIdx.y;               // K-tile
  u16* base = Bf + ((((size_t)bx * 16 + tt) * 4 + wc) * 8) * 512;
  const int l = tid & 63;
  #pragma unroll
  for (int fh = 0; fh < 2; ++fh) {
    const int f = (tid >> 6) * 2 + fh;     // 0..7
    const int nn = f >> 1, ks = f & 1;
    const int cl = nn * 16 + (l & 15);
    const int kl = ks * 32 + (l >> 4) * 8;
    u16 tmp[8];
    #pragma unroll
    for (int j = 0; j < 8; ++j) tmp[j] = f2bf(tile[kl + j][cl]);
    uint4 v;
    v.x = (unsigned)tmp[0] | ((unsigned)tmp[1] << 16);
    v.y = (unsigned)tmp[2] | ((unsigned)tmp[3] << 16);
    v.z = (unsigned)tmp[4] | ((unsigned)tmp[5] << 16);
    v.w = (unsigned)tmp[6] | ((unsigned)tmp[7] << 16);
    *reinterpret_cast<uint4*>(base + (size_t)f * 512 + (size_t)l * 8) = v;
  }
  if (r4 == 0)
    part[(size_t)blockIdx.y * OUTF + n0 + c] =
        psum[0][c] + psum[1][c] + psum[2][c] + psum[3][c];
}

__global__ void __launch_bounds__(256) k_wsq_final(const float* __restrict__ part,
                                                   float* __restrict__ wsq) {
  const int col = blockIdx.x * 256 + threadIdx.x;
  float s = 0.f;
  #pragma unroll
  for (int kb = 0; kb < 16; ++kb) s += part[(size_t)kb * OUTF + col];
  wsq[col] = s;
}

// ---- fused GEMM (template for ablation): out = xsq + wsq - 2 * (x @ w) ----
// 256x256 tile, BK=64, 8 waves (2Mx4N). A: 64 KiB LDS double-buffer (T2
// swizzle, gload_lds). B: fragment-major global loads, reg-dbuf. ONE barrier
// per K-tile: vmcnt(0)+lgkmcnt(0) -> barrier -> issue A(t+1)+B(t+1) (full-tile
// latency cover) -> 16 ds_read + 64 MFMA.
// DO_STAGE=0: zero VMEM (constant B, garbage LDS) -> pure compute skeleton.
// DO_DS=0: A-frags from registers. DO_MFMA=0: frags kept alive via asm.
template<int DO_STAGE, int DO_DS, int DO_MFMA>
__global__ void __launch_bounds__(512, 2) k_gemm_t(const u16* __restrict__ A,
                                                   const u16* __restrict__ Bf,
                                                   const float* __restrict__ xsq,
                                                   const float* __restrict__ wsq,
                                                   float* __restrict__ out) {
  extern __shared__ __attribute__((aligned(16))) char lds_raw[];  // 2 x 32 KB (A)

  const int tid = threadIdx.x;
  const int wave = tid >> 6, lane = tid & 63;
  const int bx = blockIdx.x & 7;           // XCD-pinned N strip
  const int by = blockIdx.x >> 3;
  const int rowBase = by * BM;
  const int colBase = bx * BN;
  const int wr = wave >> 2, wc = wave & 3; // 2 (M) x 4 (N)

  // A staging (linear LDS dest, pre-swizzled global source)
  const int srow = tid >> 3;                                          // 0..63
  const int ke   = (((tid & 7) * 16) ^ (((tid >> 3) & 7) << 4)) >> 1;
  const u16* aS = A + (size_t)(rowBase + srow) * INF + ke;
  char* ldsw = lds_raw + tid * 16;

  auto STAGE_A = [&](int parity, int t) {
    if constexpr (DO_STAGE) {
      const int kk = t * BK;
      char* dst = ldsw + parity * 32768;
      #pragma unroll
      for (int i = 0; i < 4; ++i)
        load_lds16(aS + (size_t)(i * 64) * INF + kk, dst + i * 8192);
    }
  };

  // fragment read addressing (A, swizzled)
  const int rf  = lane & 15;
  const int hi  = lane >> 4;
  const int swz = (rf & 7) << 4;
  const int aRd = (wr * 128 + rf) * 128;

  // fragment-major B base for this wave; tile t at +t*16384, frag f at +f*512
  const u16* bBase = Bf + ((((size_t)bx * 16 + 0) * 4 + wc) * 8) * 512
                     + (size_t)lane * 8;

  f32x4 acc[8][4] = {};
  bf16x8 bc[8], bn[8];

  if constexpr (!DO_STAGE) {
    union { u16 s[8]; bf16x8 v; } o;
    #pragma unroll
    for (int j = 0; j < 8; ++j) o.s[j] = 0x3F80;   // 1.0bf16
    #pragma unroll
    for (int f = 0; f < 8; ++f) { bc[f] = o.v; bn[f] = o.v; }
  }

  // prologue: A(0) stage + B(0) regs
  STAGE_A(0, 0);
  if constexpr (DO_STAGE) {
    #pragma unroll
    for (int f = 0; f < 8; ++f)
      bc[f] = *reinterpret_cast<const bf16x8*>(bBase + f * 512);
  }

  #pragma unroll
  for (int t = 0; t < NT; ++t) {
    // own stages for tile t landed + own reads of the other buffer retired;
    // barrier => globally true => safe to read buf[t&1] and overwrite other.
    asm volatile("s_waitcnt vmcnt(0) lgkmcnt(0)" ::: "memory");
    __builtin_amdgcn_s_barrier();

    if (t + 1 < NT) {
      STAGE_A((t + 1) & 1, t + 1);          // full-tile cover until next head
      if constexpr (DO_STAGE) {
        const u16* bT = bBase + (size_t)(t + 1) * 16384;
        #pragma unroll
        for (int f = 0; f < 8; ++f)
          bn[f] = *reinterpret_cast<const bf16x8*>(bT + f * 512);
      }
    }

    const char* buf = lds_raw + (t & 1) * 32768;
    #pragma unroll
    for (int mh = 0; mh < 2; ++mh) {
      bf16x8 a[4][2];
      #pragma unroll
      for (int mm = 0; mm < 4; ++mm)
        #pragma unroll
        for (int ks = 0; ks < 2; ++ks) {
          if constexpr (DO_DS)
            a[mm][ks] = *reinterpret_cast<const bf16x8*>(
                buf + aRd + (mh * 4 + mm) * 2048 + ((ks * 64 + hi * 16) ^ swz));
          else
            a[mm][ks] = bc[mm * 2 + ks];
        }
      if constexpr (DO_MFMA) {
        __builtin_amdgcn_s_setprio(1);
        #pragma unroll
        for (int mm = 0; mm < 4; ++mm)
          #pragma unroll
          for (int nn = 0; nn < 4; ++nn)
            #pragma unroll
            for (int ks = 0; ks < 2; ++ks)
              acc[mh * 4 + mm][nn] = __builtin_amdgcn_mfma_f32_16x16x32_bf16(
                  a[mm][ks], bc[nn * 2 + ks], acc[mh * 4 + mm][nn], 0, 0, 0);
        __builtin_amdgcn_s_setprio(0);
      } else {
        #pragma unroll
        for (int mm = 0; mm < 4; ++mm)
          #pragma unroll
          for (int ks = 0; ks < 2; ++ks) {
            f32x4 ka = __builtin_bit_cast(f32x4, a[mm][ks]);
            asm volatile("" :: "v"(ka));   // keep ds_read live (rule #17)
          }
      }
    }

    if (t + 1 < NT) {
      #pragma unroll
      for (int f = 0; f < 8; ++f) bc[f] = bn[f];   // static-index rotate
    }
  }

  // ---- epilogue: C/D layout col = lane&15, row = (lane>>4)*4 + j ----
  const int cj = lane & 15;
  const int rg = hi * 4;
  #pragma unroll
  for (int m = 0; m < 8; ++m) {
    #pragma unroll
    for (int j = 0; j < 4; ++j) {
      const int row = rowBase + wr * 128 + m * 16 + rg + j;
      const float xs = xsq[row];
      #pragma unroll
      for (int n = 0; n < 4; ++n) {
        const int col = colBase + wc * 64 + n * 16 + cj;
        out[(size_t)row * OUTF + col] = xs + wsq[col] - 2.0f * acc[m][n][j];
      }
    }
  }
}

extern "C" void kernel_launch(void* const* d_in, const int* in_sizes, int n_in,
                              void* d_out, int out_size, void* d_ws, size_t ws_size,
                              hipStream_t stream) {
  const float* x = (const float*)d_in[0];
  const float* w = (const float*)d_in[1];
  float* out = (float*)d_out;

  char* ws = (char*)d_ws;
  u16* xb    = (u16*)(ws);                    // 16384*1024*2 = 33554432 B
  u16* Bf    = (u16*)(ws + 33554432);         // 2048*1024*2  =  4194304 B (fragment-major)
  float* xsq = (float*)(ws + 37748736);       // 16384*4      =    65536 B
  float* wsq = (float*)(ws + 37814272);       // 2048*4       =     8192 B
  float* prt = (float*)(ws + 37822464);       // 16*2048*4    =   131072 B

  (void)hipFuncSetAttribute(reinterpret_cast<const void*>(k_gemm_t<1, 1, 1>),
                            hipFuncAttributeMaxDynamicSharedMemorySize, 65536);
  (void)hipFuncSetAttribute(reinterpret_cast<const void*>(k_gemm_t<0, 1, 1>),
                            hipFuncAttributeMaxDynamicSharedMemorySize, 65536);

  k_convert_x<<<BATCH, 256, 0, stream>>>(x, xb, xsq);
  k_convert_w<<<dim3(OUTF / 64, INF / 64), 256, 0, stream>>>(w, Bf, prt);
  k_wsq_final<<<OUTF / 256, 256, 0, stream>>>(prt, wsq);

  // ABLATION (diagnostic, garbage output -> fully overwritten below):
  // pure compute skeleton, zero VMEM in the K-loop.
  k_gemm_t<0, 1, 1><<<512, 512, 65536, stream>>>(xb, Bf, xsq, wsq, out);

  // REAL kernel: writes every element of d_out (correct).
  k_gemm_t<1, 1, 1><<<512, 512, 65536, stream>>>(xb, Bf, xsq, wsq, out);
}

// Round 9
// 104.783 us; speedup vs baseline: 1.2545x; 1.2545x over previous
//
#include <hip/hip_runtime.h>
#include <hip/hip_bf16.h>
#include <stdint.h>

#define BATCH 16384
#define INF   1024
#define OUTF  2048

#define BM 128
#define BN 128
#define BK 64
#define NT (INF / BK)   // 16 K-tiles

using bf16x8 = __attribute__((ext_vector_type(8))) __bf16;
using f32x4  = __attribute__((ext_vector_type(4))) float;
typedef unsigned short u16;

// round-to-nearest-even f32 -> bf16 (bit pattern)
__device__ __forceinline__ u16 f2bf(float f) {
  unsigned u = __builtin_bit_cast(unsigned, f);
  u += 0x7fffu + ((u >> 16) & 1u);
  return (u16)(u >> 16);
}

__device__ __forceinline__ void load_lds16(const void* g, void* l) {
  __builtin_amdgcn_global_load_lds(
      (const __attribute__((address_space(1))) unsigned*)g,
      (__attribute__((address_space(3))) unsigned*)l, 16, 0, 0);
}

// ---- x: fp32 [BATCH][INF] -> bf16 [BATCH][INF] + row sum-of-squares (fp32) ----
__global__ void __launch_bounds__(256) k_convert_x(const float* __restrict__ x,
                                                   u16* __restrict__ xb,
                                                   float* __restrict__ xsq) {
  const int row = blockIdx.x;
  const int t = threadIdx.x;
  const float4 v = reinterpret_cast<const float4*>(x + (size_t)row * INF)[t];
  ushort4 b4;
  b4.x = f2bf(v.x); b4.y = f2bf(v.y); b4.z = f2bf(v.z); b4.w = f2bf(v.w);
  reinterpret_cast<ushort4*>(xb + (size_t)row * INF)[t] = b4;

  float s = v.x * v.x + v.y * v.y + v.z * v.z + v.w * v.w;
  #pragma unroll
  for (int off = 32; off > 0; off >>= 1) s += __shfl_xor(s, off, 64);
  __shared__ float red[4];
  if ((t & 63) == 0) red[t >> 6] = s;
  __syncthreads();
  if (t == 0) xsq[row] = red[0] + red[1] + red[2] + red[3];
}

// ---- w: fp32 [INF][OUTF] -> bf16 w^T [OUTF][INF] + fused per-column sq-partials ----
__global__ void __launch_bounds__(256) k_convert_w(const float* __restrict__ w,
                                                   u16* __restrict__ wt,
                                                   float* __restrict__ part) {
  __shared__ float tile[64][65];
  __shared__ float psum[4][64];
  const int n0 = blockIdx.x * 64;   // along OUTF
  const int k0 = blockIdx.y * 64;   // along INF
  const int t = threadIdx.x;
  const int c = t & 63, r4 = t >> 6;
  float s = 0.f;
  #pragma unroll
  for (int i = 0; i < 16; ++i) {
    int k = r4 + i * 4;
    float v = w[(size_t)(k0 + k) * OUTF + n0 + c];   // coalesced over n
    tile[k][c] = v;
    s += v * v;
  }
  psum[r4][c] = s;
  __syncthreads();
  #pragma unroll
  for (int i = 0; i < 16; ++i) {
    int n = r4 + i * 4;
    wt[(size_t)(n0 + n) * INF + k0 + c] = f2bf(tile[c][n]);  // coalesced over k
  }
  if (r4 == 0)
    part[(size_t)blockIdx.y * OUTF + n0 + c] =
        psum[0][c] + psum[1][c] + psum[2][c] + psum[3][c];
}

__global__ void __launch_bounds__(256) k_wsq_final(const float* __restrict__ part,
                                                   float* __restrict__ wsq) {
  const int col = blockIdx.x * 256 + threadIdx.x;
  float s = 0.f;
  #pragma unroll
  for (int kb = 0; kb < 16; ++kb) s += part[(size_t)kb * OUTF + col];
  wsq[col] = s;
}

// ---- fused GEMM: out = xsq[row] + wsq[col] - 2 * (x @ w) ----
// m97-faithful structure, re-targeted for CROSS-BLOCK overlap (R8 ablation:
// compute skeleton = MFMA peak; staging was additive because only ONE barrier
// domain per CU). 128x128 tile, 4 waves (2x2 of 64x64), BK=64, single-buffered
// 32 KiB static LDS, <=128 VGPR via __launch_bounds__(256,4) -> 4 independent
// blocks/CU: while one block stalls at vmcnt(0)+barrier, 3 others compute.
// T2 swizzle both-sides (linear LDS dest, pre-swizzled src, swizzled ds_read).
// XCD map: xcd=bid&7 owns N-strips {2*xcd, 2*xcd+1} -> B panel 512 KB L2-hot.
__global__ void __launch_bounds__(256, 4) k_gemm(const u16* __restrict__ A,
                                                 const u16* __restrict__ Bt,
                                                 const float* __restrict__ xsq,
                                                 const float* __restrict__ wsq,
                                                 float* __restrict__ out) {
  __shared__ __attribute__((aligned(16))) char lds[32768]; // A 16K @0, B 16K @16384

  const int tid = threadIdx.x;
  const int wave = tid >> 6, lane = tid & 63;
  const int bid = blockIdx.x;
  const int xcd = bid & 7;
  const int idx = bid >> 3;                // 0..255
  const int bxn = xcd * 2 + (idx & 1);     // 0..15  (N block, XCD-pinned pair)
  const int by  = idx >> 1;                // 0..127 (M block)
  const int rowBase = by * BM;
  const int colBase = bxn * BN;
  const int wr = (wave >> 1) & 1, wc = wave & 1;   // 2x2 waves of 64x64

  // staging (linear LDS dest = tid*16 + i*4096; pre-swizzled global source)
  const int srow = tid >> 3;                                          // 0..31
  const int ke   = (((tid & 7) * 16) ^ (((tid >> 3) & 7) << 4)) >> 1; // elem col
  const u16* aS = A  + (size_t)(rowBase + srow) * INF + ke;
  const u16* bS = Bt + (size_t)(colBase + srow) * INF + ke;
  char* ldsw = lds + tid * 16;

  // fragment read addressing (swizzled); rows are 128 B
  const int rf  = lane & 15;
  const int hi  = lane >> 4;                 // 0..3
  const int swz = (rf & 7) << 4;
  const int aRd = (wr * 64 + rf) * 128;              // + mm*2048 + ko
  const int bRd = 16384 + (wc * 64 + rf) * 128;      // + nn*2048 + ko

  f32x4 acc[4][4] = {};

  for (int t = 0; t < NT; ++t) {
    __builtin_amdgcn_s_barrier();            // everyone done reading prev tile
    const int kk = t * BK;
    #pragma unroll
    for (int i = 0; i < 4; ++i)              // A rows [i*32, i*32+32)
      load_lds16(aS + (size_t)(i * 32) * INF + kk, ldsw + i * 4096);
    #pragma unroll
    for (int i = 0; i < 4; ++i)              // B rows
      load_lds16(bS + (size_t)(i * 32) * INF + kk, ldsw + 16384 + i * 4096);
    asm volatile("s_waitcnt vmcnt(0)" ::: "memory");
    __builtin_amdgcn_s_barrier();            // tile t staged for all waves

    #pragma unroll
    for (int ks = 0; ks < 2; ++ks) {
      const int ko = (ks * 64 + hi * 16) ^ swz;
      bf16x8 b[4];
      #pragma unroll
      for (int nn = 0; nn < 4; ++nn)
        b[nn] = *reinterpret_cast<const bf16x8*>(lds + bRd + nn * 2048 + ko);
      __builtin_amdgcn_s_setprio(1);
      #pragma unroll
      for (int mm = 0; mm < 4; ++mm) {
        bf16x8 a = *reinterpret_cast<const bf16x8*>(lds + aRd + mm * 2048 + ko);
        #pragma unroll
        for (int nn = 0; nn < 4; ++nn)
          acc[mm][nn] = __builtin_amdgcn_mfma_f32_16x16x32_bf16(
              a, b[nn], acc[mm][nn], 0, 0, 0);
      }
      __builtin_amdgcn_s_setprio(0);
    }
  }

  // ---- epilogue: C/D layout col = lane&15, row = (lane>>4)*4 + j ----
  const int cj = lane & 15;
  const int rg = hi * 4;
  #pragma unroll
  for (int m = 0; m < 4; ++m) {
    #pragma unroll
    for (int j = 0; j < 4; ++j) {
      const int row = rowBase + wr * 64 + m * 16 + rg + j;
      const float xs = xsq[row];
      #pragma unroll
      for (int n = 0; n < 4; ++n) {
        const int col = colBase + wc * 64 + n * 16 + cj;
        out[(size_t)row * OUTF + col] = xs + wsq[col] - 2.0f * acc[m][n][j];
      }
    }
  }
}

extern "C" void kernel_launch(void* const* d_in, const int* in_sizes, int n_in,
                              void* d_out, int out_size, void* d_ws, size_t ws_size,
                              hipStream_t stream) {
  const float* x = (const float*)d_in[0];
  const float* w = (const float*)d_in[1];
  float* out = (float*)d_out;

  char* ws = (char*)d_ws;
  u16* xb    = (u16*)(ws);                    // 16384*1024*2 = 33554432 B
  u16* wt    = (u16*)(ws + 33554432);         // 2048*1024*2  =  4194304 B (B^T)
  float* xsq = (float*)(ws + 37748736);       // 16384*4      =    65536 B
  float* wsq = (float*)(ws + 37814272);       // 2048*4       =     8192 B
  float* prt = (float*)(ws + 37822464);       // 16*2048*4    =   131072 B

  k_convert_x<<<BATCH, 256, 0, stream>>>(x, xb, xsq);
  k_convert_w<<<dim3(OUTF / 64, INF / 64), 256, 0, stream>>>(w, wt, prt);
  k_wsq_final<<<OUTF / 256, 256, 0, stream>>>(prt, wsq);
  k_gemm<<<(BATCH / BM) * (OUTF / BN), 256, 0, stream>>>(xb, wt, xsq, wsq, out);
}